// Round 1
// baseline (22541.331 us; speedup 1.0000x reference)
//
#include <hip/hip_runtime.h>

// Round 1: full split-bf16 MFMA implementation.
// Pipeline: embed -> LSTM1 (fused-input MFMA scan, 776 WGs) -> BN2 ->
//           per-layer [xg GEMM (MFMA) + single-WG LSTM2 scan] -> BN3+MLP head.
// All recurrent math uses hi/lo bf16 split (3 MFMA terms) for ~fp32 accuracy.

typedef short  bf16x8 __attribute__((ext_vector_type(8)));
typedef float  f32x4  __attribute__((ext_vector_type(4)));

#define DEVI static __device__ __forceinline__

constexpr int   T1c   = 20;
constexpr int   EMBc  = 32;
constexpr int   H1c   = 64;
constexpr int   H2c   = 128;
constexpr int   LMAXc = 1024;
constexpr int   Ntot  = 24832;           // sum of lengths
constexpr int   NTc   = Ntot * T1c;      // 496640
constexpr int   R2c   = 32 * LMAXc;      // 32768
constexpr float EPSc  = 1e-5f;

DEVI unsigned short f2bf(float x) {      // RNE float->bf16
    unsigned u = __float_as_uint(x);
    u += 0x7FFFu + ((u >> 16) & 1u);
    return (unsigned short)(u >> 16);
}
DEVI float bf2f(unsigned short h) { return __uint_as_float((unsigned)h << 16); }
DEVI void split2(float x, unsigned short &hi, unsigned short &lo) {
    hi = f2bf(x);
    lo = f2bf(x - bf2f(hi));
}
DEVI float sigm(float x)   { return 1.f / (1.f + __expf(-x)); }
DEVI float tanhf_(float x) { return 1.f - 2.f / (1.f + __expf(2.f * x)); }

// ---------------- weight prep: f32 -> (hi,lo) bf16, row stride OS, col offset KO
__global__ void __launch_bounds__(256)
k_prep(const float* __restrict__ in, unsigned short* __restrict__ hi,
       unsigned short* __restrict__ lo, int R, int K, int OS, int KO)
{
    int i = blockIdx.x * 256 + threadIdx.x;
    if (i >= R * K) return;
    int r = i / K, k = i - r * K;
    unsigned short h, l; split2(in[i], h, l);
    hi[r * OS + KO + k] = h;
    lo[r * OS + KO + k] = l;
}

// ---------------- embedding: x = embed_w[id] * id, split into seq1 (row stride 64)
__global__ void __launch_bounds__(256)
k_embed(const int* __restrict__ atoms, const float* __restrict__ ew,
        unsigned short* __restrict__ shi, unsigned short* __restrict__ slo)
{
    int i = blockIdx.x * 256 + threadIdx.x;
    if (i >= NTc * EMBc) return;
    int nt = i / EMBc, e = i - nt * EMBc;
    int id = atoms[nt];
    float v = ew[id * EMBc + e] * (float)id;
    unsigned short h, l; split2(v, h, l);
    shi[nt * H1c + e] = h;
    slo[nt * H1c + e] = l;
}

// ---------------- LSTM1 scan: 256 thr = 4 waves, 32 samples/WG, fused input GEMM.
// wave wv owns d-slice [16wv,16wv+16); computes gates i,f,g,o for both 16-sample
// m-tiles via mfma_f32_16x16x32_bf16.  W ([Wih|Whh] combined, row stride 128)
// preloaded to VGPRs.  h/x staged split-bf16 in LDS; c lives in accregs.
template <int KIN>
__global__ void __launch_bounds__(256)
k_scan1(unsigned short* seq_hi, unsigned short* seq_lo,
        const unsigned short* __restrict__ Whi, const unsigned short* __restrict__ Wlo,
        const float* __restrict__ bptr, float* __restrict__ dacc,
        int accum, int writeSeq)
{
    constexpr int KTOT = KIN + 64;
    constexpr int KCH  = KTOT / 32;
    constexpr int SX   = KTOT + 8;                // pad; keeps 16B alignment
    __shared__ alignas(16) unsigned short xh_hi[32 * SX];
    __shared__ alignas(16) unsigned short xh_lo[32 * SX];

    const int tid  = threadIdx.x;
    const int lane = tid & 63;
    const int wv   = tid >> 6;      // 0..3 : d-slice
    const int l16  = lane & 15;
    const int quad = lane >> 4;
    const int n0   = blockIdx.x * 32;
    const int d    = wv * 16 + l16;

    float bias[4];
#pragma unroll
    for (int g = 0; g < 4; ++g) bias[g] = bptr[g * 64 + d];

    // preload weight B-fragments (constant over t): [kc][gate]
    bf16x8 wbh[KCH][4], wbl[KCH][4];
#pragma unroll
    for (int kc = 0; kc < KCH; ++kc) {
        const int kb = kc * 32 + quad * 8;
#pragma unroll
        for (int g = 0; g < 4; ++g) {
            const int j = g * 64 + d;
            wbh[kc][g] = *(const bf16x8*)&Whi[j * 128 + kb];
            wbl[kc][g] = *(const bf16x8*)&Wlo[j * 128 + kb];
        }
    }

    f32x4 c[2];
    c[0] = {1.f, 1.f, 1.f, 1.f};
    c[1] = {1.f, 1.f, 1.f, 1.f};

    // h init = ones (this thread's own write slots cover the whole h region)
#pragma unroll
    for (int mt = 0; mt < 2; ++mt)
#pragma unroll
        for (int r = 0; r < 4; ++r) {
            int s = mt * 16 + quad * 4 + r;
            xh_hi[s * SX + KIN + d] = 0x3F80;
            xh_lo[s * SX + KIN + d] = 0;
        }

#pragma unroll 1
    for (int t = 0; t < T1c; ++t) {
        // stage x_t (cols 0..KIN-1)
        for (int idx = tid; idx < 32 * KIN; idx += 256) {
            int s = idx / KIN, k = idx - s * KIN;
            int row = (n0 + s) * T1c + t;
            xh_hi[s * SX + k] = seq_hi[row * H1c + k];
            xh_lo[s * SX + k] = seq_lo[row * H1c + k];
        }
        __syncthreads();

        f32x4 acc[2][4];
#pragma unroll
        for (int mt = 0; mt < 2; ++mt)
#pragma unroll
            for (int g = 0; g < 4; ++g)
                acc[mt][g] = {bias[g], bias[g], bias[g], bias[g]};

#pragma unroll
        for (int kc = 0; kc < KCH; ++kc) {
            const int kb = kc * 32 + quad * 8;
            bf16x8 ah[2], al[2];
#pragma unroll
            for (int mt = 0; mt < 2; ++mt) {
                const int ro = (mt * 16 + l16) * SX + kb;
                ah[mt] = *(const bf16x8*)&xh_hi[ro];
                al[mt] = *(const bf16x8*)&xh_lo[ro];
            }
#pragma unroll
            for (int g = 0; g < 4; ++g)
#pragma unroll
                for (int mt = 0; mt < 2; ++mt) {
                    acc[mt][g] = __builtin_amdgcn_mfma_f32_16x16x32_bf16(ah[mt], wbh[kc][g], acc[mt][g], 0, 0, 0);
                    acc[mt][g] = __builtin_amdgcn_mfma_f32_16x16x32_bf16(ah[mt], wbl[kc][g], acc[mt][g], 0, 0, 0);
                    acc[mt][g] = __builtin_amdgcn_mfma_f32_16x16x32_bf16(al[mt], wbh[kc][g], acc[mt][g], 0, 0, 0);
                }
        }
        __syncthreads();   // all frag reads done before h is rewritten

#pragma unroll
        for (int mt = 0; mt < 2; ++mt)
#pragma unroll
            for (int r = 0; r < 4; ++r) {
                float iv = sigm(acc[mt][0][r]);
                float fv = sigm(acc[mt][1][r]);
                float gv = tanhf_(acc[mt][2][r]);
                float ov = sigm(acc[mt][3][r]);
                float cv = fv * c[mt][r] + iv * gv;
                c[mt][r] = cv;
                float hv = ov * tanhf_(cv);
                unsigned short hh, hl; split2(hv, hh, hl);
                int s = mt * 16 + quad * 4 + r;   // C-layout: row = quad*4+reg
                xh_hi[s * SX + KIN + d] = hh;
                xh_lo[s * SX + KIN + d] = hl;
                if (writeSeq) {
                    int row = (n0 + s) * T1c + t;
                    seq_hi[row * H1c + d] = hh;
                    seq_lo[row * H1c + d] = hl;
                }
                if (t == T1c - 1) {
                    int o = (n0 + s) * H1c + d;
                    float val = 0.25f * (hv + cv);   // mean over 4 layers of h+c
                    if (accum) dacc[o] += val; else dacc[o] = val;
                }
            }
        // next iteration's stage+barrier provides write->read ordering
    }
}

// ---------------- BN2 stats: per structure, stats over padded (1024*64) incl. zeros
__global__ void __launch_bounds__(256)
k_bn2_stats(const int* __restrict__ lens, const float* __restrict__ dacc,
            float* __restrict__ stats)
{
    int b = blockIdx.x;
    int off = 0;
    for (int i = 0; i < b; ++i) off += lens[i];
    int len = lens[b];
    const float* base = dacc + (long)off * H1c;
    float s = 0.f, ss = 0.f;
    int total = len * H1c;
    for (int i = threadIdx.x; i < total; i += 256) { float v = base[i]; s += v; ss += v * v; }
    __shared__ float rs[256], rss[256];
    rs[threadIdx.x] = s; rss[threadIdx.x] = ss;
    __syncthreads();
    for (int st = 128; st > 0; st >>= 1) {
        if (threadIdx.x < st) { rs[threadIdx.x] += rs[threadIdx.x + st]; rss[threadIdx.x] += rss[threadIdx.x + st]; }
        __syncthreads();
    }
    if (threadIdx.x == 0) {
        float m = rs[0] / (float)(LMAXc * H1c);
        float v = rss[0] / (float)(LMAXc * H1c) - m * m;
        stats[b]      = m;
        stats[32 + b] = rsqrtf(fmaxf(v, 0.f) + EPSc);
        stats[64 + b] = (float)off;
    }
}

// ---------------- BN2 apply -> LSTM2 layer-0 input (B,1024,64) split-bf16, stride 64
__global__ void __launch_bounds__(256)
k_bn2_apply(const float* __restrict__ dacc, const float* __restrict__ stats,
            const int* __restrict__ lens, const float* __restrict__ g,
            const float* __restrict__ bb,
            unsigned short* __restrict__ ohi, unsigned short* __restrict__ olo)
{
    int i = blockIdx.x * 256 + threadIdx.x;
    if (i >= R2c * H1c) return;
    int rr = i / H1c, k = i - rr * H1c;
    int b = rr >> 10, p = rr & 1023;
    int off = (int)stats[64 + b];
    float x = (p < lens[b]) ? dacc[(off + p) * H1c + k] : 0.f;
    float y = (x - stats[b]) * stats[32 + b] * g[b] + bb[b];
    unsigned short h, l; split2(y, h, l);
    ohi[rr * H1c + k] = h;
    olo[rr * H1c + k] = l;
}

// ---------------- xg GEMM for LSTM2: xg[t*32+b][j] = in[b*1024+t] . Wih[j] + bias[j]
// 32 rows / WG, wave wv covers 128 cols (8 n-tiles); split-bf16 (3 MFMA terms).
template <int KIN2>
__global__ void __launch_bounds__(256)
k_xg2(const unsigned short* __restrict__ in_hi, const unsigned short* __restrict__ in_lo,
      const unsigned short* __restrict__ Whi, const unsigned short* __restrict__ Wlo,
      const float* __restrict__ bias, float* __restrict__ xg)
{
    constexpr int SX  = KIN2 + 8;
    constexpr int KCH = KIN2 / 32;
    __shared__ alignas(16) unsigned short a_hi[32 * SX];
    __shared__ alignas(16) unsigned short a_lo[32 * SX];
    const int tid = threadIdx.x, lane = tid & 63, wv = tid >> 6;
    const int l16 = lane & 15, quad = lane >> 4;
    const int r0 = blockIdx.x * 32;

    for (int idx = tid; idx < 32 * KIN2; idx += 256) {
        int s = idx / KIN2, k = idx - s * KIN2;
        int src = (r0 + s) * KIN2 + k;
        a_hi[s * SX + k] = in_hi[src];
        a_lo[s * SX + k] = in_lo[src];
    }
    __syncthreads();

    f32x4 acc[2][8];
#pragma unroll
    for (int mt = 0; mt < 2; ++mt)
#pragma unroll
        for (int nt = 0; nt < 8; ++nt) {
            float bv = bias[wv * 128 + nt * 16 + l16];
            acc[mt][nt] = {bv, bv, bv, bv};
        }

#pragma unroll
    for (int kc = 0; kc < KCH; ++kc) {
        const int kb = kc * 32 + quad * 8;
        bf16x8 ah[2], al[2];
#pragma unroll
        for (int mt = 0; mt < 2; ++mt) {
            const int ro = (mt * 16 + l16) * SX + kb;
            ah[mt] = *(const bf16x8*)&a_hi[ro];
            al[mt] = *(const bf16x8*)&a_lo[ro];
        }
#pragma unroll
        for (int nt = 0; nt < 8; ++nt) {
            const int j = wv * 128 + nt * 16 + l16;
            bf16x8 bh = *(const bf16x8*)&Whi[j * 128 + kb];
            bf16x8 bl = *(const bf16x8*)&Wlo[j * 128 + kb];
#pragma unroll
            for (int mt = 0; mt < 2; ++mt) {
                acc[mt][nt] = __builtin_amdgcn_mfma_f32_16x16x32_bf16(ah[mt], bh, acc[mt][nt], 0, 0, 0);
                acc[mt][nt] = __builtin_amdgcn_mfma_f32_16x16x32_bf16(ah[mt], bl, acc[mt][nt], 0, 0, 0);
                acc[mt][nt] = __builtin_amdgcn_mfma_f32_16x16x32_bf16(al[mt], bh, acc[mt][nt], 0, 0, 0);
            }
        }
    }
    // store transposed to [t][b] ordering so the scan reads contiguous blocks
#pragma unroll
    for (int mt = 0; mt < 2; ++mt)
#pragma unroll
        for (int nt = 0; nt < 8; ++nt)
#pragma unroll
            for (int r = 0; r < 4; ++r) {
                int rr = r0 + mt * 16 + quad * 4 + r;   // = b*1024+p
                int b = rr >> 10, p = rr & 1023;
                xg[(p * 32 + b) * 512 + wv * 128 + nt * 16 + l16] = acc[mt][nt][r];
            }
}

// ---------------- LSTM2 scan: ONE workgroup, 512 thr = 8 waves (wave = d-slice),
// both m-tiles per wave; Whh hi/lo fragments register-resident (no per-step L2).
__global__ void __launch_bounds__(512)
k_scan2(const float* __restrict__ xg, const unsigned short* __restrict__ Whi,
        const unsigned short* __restrict__ Wlo,
        unsigned short* seq_hi, unsigned short* seq_lo,
        float* __restrict__ c2acc, int accum, int writeSeq)
{
    constexpr int SH = H2c + 8;                    // 136
    __shared__ alignas(16) unsigned short h_hi[32 * SH];
    __shared__ alignas(16) unsigned short h_lo[32 * SH];
    const int tid = threadIdx.x, lane = tid & 63, wv = tid >> 6;  // wv = 0..7
    const int l16 = lane & 15, quad = lane >> 4;
    const int d = wv * 16 + l16;

    // preload Whh fragments: [kc][gate]
    bf16x8 wbh[4][4], wbl[4][4];
#pragma unroll
    for (int kc = 0; kc < 4; ++kc) {
        const int kb = kc * 32 + quad * 8;
#pragma unroll
        for (int g = 0; g < 4; ++g) {
            const int j = g * 128 + d;
            wbh[kc][g] = *(const bf16x8*)&Whi[j * 128 + kb];
            wbl[kc][g] = *(const bf16x8*)&Wlo[j * 128 + kb];
        }
    }

    f32x4 c[2];
    c[0] = {1.f, 1.f, 1.f, 1.f};
    c[1] = {1.f, 1.f, 1.f, 1.f};
#pragma unroll
    for (int mt = 0; mt < 2; ++mt)
#pragma unroll
        for (int r = 0; r < 4; ++r) {
            int s = mt * 16 + quad * 4 + r;
            h_hi[s * SH + d] = 0x3F80;             // bf16(1.0)
            h_lo[s * SH + d] = 0;
        }
    __syncthreads();

#pragma unroll 1
    for (int t = 0; t < LMAXc; ++t) {
        const float* xr = xg + t * 32 * 512;
        f32x4 acc[2][4];
#pragma unroll
        for (int mt = 0; mt < 2; ++mt)
#pragma unroll
            for (int g = 0; g < 4; ++g) {
                const int col = g * 128 + d;
                f32x4 a;
#pragma unroll
                for (int r = 0; r < 4; ++r)
                    a[r] = xr[(mt * 16 + quad * 4 + r) * 512 + col];
                acc[mt][g] = a;
            }
#pragma unroll
        for (int kc = 0; kc < 4; ++kc) {
            const int kb = kc * 32 + quad * 8;
            bf16x8 ah[2], al[2];
#pragma unroll
            for (int mt = 0; mt < 2; ++mt) {
                const int ro = (mt * 16 + l16) * SH + kb;
                ah[mt] = *(const bf16x8*)&h_hi[ro];
                al[mt] = *(const bf16x8*)&h_lo[ro];
            }
#pragma unroll
            for (int g = 0; g < 4; ++g)
#pragma unroll
                for (int mt = 0; mt < 2; ++mt) {
                    acc[mt][g] = __builtin_amdgcn_mfma_f32_16x16x32_bf16(ah[mt], wbh[kc][g], acc[mt][g], 0, 0, 0);
                    acc[mt][g] = __builtin_amdgcn_mfma_f32_16x16x32_bf16(ah[mt], wbl[kc][g], acc[mt][g], 0, 0, 0);
                    acc[mt][g] = __builtin_amdgcn_mfma_f32_16x16x32_bf16(al[mt], wbh[kc][g], acc[mt][g], 0, 0, 0);
                }
        }
        __syncthreads();
#pragma unroll
        for (int mt = 0; mt < 2; ++mt)
#pragma unroll
            for (int r = 0; r < 4; ++r) {
                float iv = sigm(acc[mt][0][r]);
                float fv = sigm(acc[mt][1][r]);
                float gv = tanhf_(acc[mt][2][r]);
                float ov = sigm(acc[mt][3][r]);
                float cv = fv * c[mt][r] + iv * gv;
                c[mt][r] = cv;
                float hv = ov * tanhf_(cv);
                unsigned short hh, hl; split2(hv, hh, hl);
                const int sr = mt * 16 + quad * 4 + r;
                h_hi[sr * SH + d] = hh;
                h_lo[sr * SH + d] = hl;
                if (writeSeq) {
                    int row = sr * LMAXc + t;
                    seq_hi[row * H2c + d] = hh;
                    seq_lo[row * H2c + d] = hl;
                }
                if (t == LMAXc - 1) {
                    int o = sr * H2c + d;
                    float val = 0.25f * cv;        // mean of final c over layers
                    if (accum) c2acc[o] += val; else c2acc[o] = val;
                }
            }
        __syncthreads();
    }
}

// ---------------- head: BN3 + MLP + relu(sum), single WG fp32
DEVI void bn_rows_dev(float* X, int K, const float* g, const float* bb,
                      float* mv, int tid)
{
    __syncthreads();
    if (tid < 32) {
        float s = 0.f, ss = 0.f;
        const float* r = X + tid * K;
        for (int k = 0; k < K; ++k) { float v = r[k]; s += v; ss += v * v; }
        float m = s / (float)K;
        float vv = ss / (float)K - m * m;
        mv[tid]      = m;
        mv[32 + tid] = rsqrtf(fmaxf(vv, 0.f) + EPSc);
    }
    __syncthreads();
    for (int i = tid; i < 32 * K; i += 256) {
        int b = i / K;
        X[i] = (X[i] - mv[b]) * mv[32 + b] * g[b] + bb[b];
    }
    __syncthreads();
}

DEVI void lin_dev(const float* X, int K, const float* W, const float* bias,
                  int NO, float* Y, int relu, int tid)
{
    __syncthreads();
    for (int i = tid; i < 32 * NO; i += 256) {
        int b = i / NO, j = i - b * NO;
        float a = bias[j];
        const float* xr = X + b * K;
        const float* wr = W + j * K;
        for (int k = 0; k < K; ++k) a += xr[k] * wr[k];
        Y[i] = relu ? fmaxf(a, 0.f) : a;
    }
    __syncthreads();
}

__global__ void __launch_bounds__(256)
k_head(const float* __restrict__ c2, const float* __restrict__ g3, const float* __restrict__ bb3,
       const float* w1, const float* b1, const float* w2, const float* b2,
       const float* w22, const float* b22, const float* w3, const float* b3,
       const float* w4, const float* b4, const float* w5, const float* b5,
       float* __restrict__ out)
{
    __shared__ float A[32 * 128];
    __shared__ float Bf[32 * 128];
    __shared__ float mv[64];
    const int tid = threadIdx.x;

    for (int i = tid; i < 32 * 128; i += 256) A[i] = c2[i];
    bn_rows_dev(A, 128, g3, bb3, mv, tid);
    lin_dev(A, 128, w1, b1, 128, Bf, 1, tid);
    lin_dev(Bf, 128, w2, b2, 64, A, 1, tid);
    bn_rows_dev(A, 64, g3, bb3, mv, tid);
    lin_dev(A, 64, w22, b22, 64, Bf, 1, tid);
    lin_dev(Bf, 64, w3, b3, 32, A, 1, tid);
    lin_dev(A, 32, w4, b4, 32, Bf, 1, tid);
    lin_dev(Bf, 32, w5, b5, 16, A, 0, tid);
    if (tid < 32) {
        float s = 0.f;
        for (int j = 0; j < 16; ++j) s += A[tid * 16 + j];
        out[tid] = fmaxf(s, 0.f);
    }
}

// ---------------- host
extern "C" void kernel_launch(void* const* d_in, const int* in_sizes, int n_in,
                              void* d_out, int out_size, void* d_ws, size_t ws_size,
                              hipStream_t stream)
{
    const int*   atoms  = (const int*)d_in[0];
    const int*   lens   = (const int*)d_in[2];
    const float* embw   = (const float*)d_in[5];
    const float* l1Wih0 = (const float*)d_in[6];
    const float* l1Whh0 = (const float*)d_in[7];
    const float* l1b0   = (const float*)d_in[8];
    const float* l1Wih  = (const float*)d_in[9];
    const float* l1Whh  = (const float*)d_in[10];
    const float* l1b    = (const float*)d_in[11];
    const float* l2Wih0 = (const float*)d_in[12];
    const float* l2Whh0 = (const float*)d_in[13];
    const float* l2b0   = (const float*)d_in[14];
    const float* l2Wih  = (const float*)d_in[15];
    const float* l2Whh  = (const float*)d_in[16];
    const float* l2b    = (const float*)d_in[17];
    const float* bn2g   = (const float*)d_in[18];
    const float* bn2b   = (const float*)d_in[19];
    const float* bn3g   = (const float*)d_in[20];
    const float* bn3b   = (const float*)d_in[21];
    const float* w1  = (const float*)d_in[22]; const float* b1  = (const float*)d_in[23];
    const float* w2  = (const float*)d_in[24]; const float* b2  = (const float*)d_in[25];
    const float* w22 = (const float*)d_in[26]; const float* b22 = (const float*)d_in[27];
    const float* w3  = (const float*)d_in[28]; const float* b3  = (const float*)d_in[29];
    const float* w4  = (const float*)d_in[30]; const float* b4  = (const float*)d_in[31];
    const float* w5  = (const float*)d_in[32]; const float* b5  = (const float*)d_in[33];
    float* out = (float*)d_out;

    char* base = (char*)d_ws;
    size_t off = 0;
    auto take = [&](size_t bytes) -> char* {
        char* p = base + off;
        off = (off + bytes + 255) & ~(size_t)255;
        return p;
    };
    unsigned short* seq1h = (unsigned short*)take((size_t)NTc * H1c * 2);   // 63.6 MB
    unsigned short* seq1l = (unsigned short*)take((size_t)NTc * H1c * 2);
    float*          dacc  = (float*)take((size_t)Ntot * H1c * 4);           // 6.4 MB
    unsigned short* w1h   = (unsigned short*)take((size_t)4 * 256 * 128 * 2);
    unsigned short* w1l   = (unsigned short*)take((size_t)4 * 256 * 128 * 2);
    unsigned short* whhh  = (unsigned short*)take((size_t)4 * 512 * 128 * 2);
    unsigned short* whhl  = (unsigned short*)take((size_t)4 * 512 * 128 * 2);
    unsigned short* wihh  = (unsigned short*)take((size_t)4 * 512 * 128 * 2);
    unsigned short* wihl  = (unsigned short*)take((size_t)4 * 512 * 128 * 2);
    unsigned short* seq2h = (unsigned short*)take((size_t)R2c * H2c * 2);   // 8.4 MB
    unsigned short* seq2l = (unsigned short*)take((size_t)R2c * H2c * 2);
    float*          xg2   = (float*)take((size_t)R2c * 512 * 4);            // 67 MB
    float*          stats = (float*)take(1024);
    float*          c2    = (float*)take((size_t)32 * 128 * 4);

    auto prep = [&](const float* src, unsigned short* dh, unsigned short* dl,
                    int R, int K, int OS, int KO) {
        int n = R * K;
        k_prep<<<(n + 255) / 256, 256, 0, stream>>>(src, dh, dl, R, K, OS, KO);
    };

    // LSTM1 combined [Wih | Whh], row stride 128
    prep(l1Wih0, w1h, w1l, 256, 32, 128, 0);
    prep(l1Whh0, w1h, w1l, 256, 64, 128, 32);
    for (int l = 1; l < 4; ++l) {
        prep(l1Wih + (l - 1) * 256 * 64, w1h + l * 256 * 128, w1l + l * 256 * 128, 256, 64, 128, 0);
        prep(l1Whh + (l - 1) * 256 * 64, w1h + l * 256 * 128, w1l + l * 256 * 128, 256, 64, 128, 64);
    }
    // LSTM2 Whh (row stride 128) and Wih (row stride 128, layer0 K=64)
    prep(l2Whh0, whhh, whhl, 512, 128, 128, 0);
    for (int l = 1; l < 4; ++l)
        prep(l2Whh + (l - 1) * 512 * 128, whhh + l * 512 * 128, whhl + l * 512 * 128, 512, 128, 128, 0);
    prep(l2Wih0, wihh, wihl, 512, 64, 128, 0);
    for (int l = 1; l < 4; ++l)
        prep(l2Wih + (l - 1) * 512 * 128, wihh + l * 512 * 128, wihl + l * 512 * 128, 512, 128, 128, 0);

    k_embed<<<(NTc * EMBc + 255) / 256, 256, 0, stream>>>(atoms, embw, seq1h, seq1l);

    for (int l = 0; l < 4; ++l) {
        const float* bp = (l == 0) ? l1b0 : l1b + (l - 1) * 256;
        if (l == 0)
            k_scan1<32><<<Ntot / 32, 256, 0, stream>>>(seq1h, seq1l, w1h, w1l, bp, dacc, 0, 1);
        else
            k_scan1<64><<<Ntot / 32, 256, 0, stream>>>(seq1h, seq1l,
                                                       w1h + l * 256 * 128, w1l + l * 256 * 128,
                                                       bp, dacc, 1, (l != 3) ? 1 : 0);
    }

    k_bn2_stats<<<32, 256, 0, stream>>>(lens, dacc, stats);
    k_bn2_apply<<<(R2c * H1c + 255) / 256, 256, 0, stream>>>(dacc, stats, lens, bn2g, bn2b, seq2h, seq2l);

    for (int l = 0; l < 4; ++l) {
        const float* bp = (l == 0) ? l2b0 : l2b + (l - 1) * 512;
        if (l == 0)
            k_xg2<64><<<R2c / 32, 256, 0, stream>>>(seq2h, seq2l, wihh, wihl, bp, xg2);
        else
            k_xg2<128><<<R2c / 32, 256, 0, stream>>>(seq2h, seq2l,
                                                     wihh + l * 512 * 128, wihl + l * 512 * 128, bp, xg2);
        k_scan2<<<1, 512, 0, stream>>>(xg2, whhh + l * 512 * 128, whhl + l * 512 * 128,
                                       seq2h, seq2l, c2, (l != 0) ? 1 : 0, (l != 3) ? 1 : 0);
    }

    k_head<<<1, 256, 0, stream>>>(c2, bn3g, bn3b, w1, b1, w2, b2, w22, b22,
                                  w3, b3, w4, b4, w5, b5, out);

    (void)in_sizes; (void)n_in; (void)out_size; (void)ws_size;
}

// Round 2
// 20945.868 us; speedup vs baseline: 1.0762x; 1.0762x over previous
//
#include <hip/hip_runtime.h>

// Round 2: k_scan2 latency restructure.
//  - xg register double-buffer prefetch (HBM latency off the critical path)
//  - xg layout [t*32+b][d*4+g] -> float4 loads (8 dwordx4 vs 32 dword)
//  - ping-pong LDS h buffers -> single __syncthreads per step (was 2)
//  - seq2 packed (hi|lo) u32, t-major -> 8 coalesced u32 stores (was 16 scattered)
// Numerics identical to Round 1 (3-term split-bf16 everywhere).

typedef short  bf16x8 __attribute__((ext_vector_type(8)));
typedef float  f32x4  __attribute__((ext_vector_type(4)));

#define DEVI static __device__ __forceinline__

constexpr int   T1c   = 20;
constexpr int   EMBc  = 32;
constexpr int   H1c   = 64;
constexpr int   H2c   = 128;
constexpr int   LMAXc = 1024;
constexpr int   Ntot  = 24832;           // sum of lengths
constexpr int   NTc   = Ntot * T1c;      // 496640
constexpr int   R2c   = 32 * LMAXc;      // 32768
constexpr float EPSc  = 1e-5f;

DEVI unsigned short f2bf(float x) {      // RNE float->bf16
    unsigned u = __float_as_uint(x);
    u += 0x7FFFu + ((u >> 16) & 1u);
    return (unsigned short)(u >> 16);
}
DEVI float bf2f(unsigned short h) { return __uint_as_float((unsigned)h << 16); }
DEVI void split2(float x, unsigned short &hi, unsigned short &lo) {
    hi = f2bf(x);
    lo = f2bf(x - bf2f(hi));
}
DEVI unsigned packbf(float x) {
    unsigned short h, l; split2(x, h, l);
    return (unsigned)h | ((unsigned)l << 16);
}
DEVI float sigm(float x)   { return 1.f / (1.f + __expf(-x)); }
DEVI float tanhf_(float x) { return 1.f - 2.f / (1.f + __expf(2.f * x)); }

// ---------------- weight prep: f32 -> (hi,lo) bf16, row stride OS, col offset KO
__global__ void __launch_bounds__(256)
k_prep(const float* __restrict__ in, unsigned short* __restrict__ hi,
       unsigned short* __restrict__ lo, int R, int K, int OS, int KO)
{
    int i = blockIdx.x * 256 + threadIdx.x;
    if (i >= R * K) return;
    int r = i / K, k = i - r * K;
    unsigned short h, l; split2(in[i], h, l);
    hi[r * OS + KO + k] = h;
    lo[r * OS + KO + k] = l;
}

// ---------------- embedding: x = embed_w[id] * id, split into seq1 (row stride 64)
__global__ void __launch_bounds__(256)
k_embed(const int* __restrict__ atoms, const float* __restrict__ ew,
        unsigned short* __restrict__ shi, unsigned short* __restrict__ slo)
{
    int i = blockIdx.x * 256 + threadIdx.x;
    if (i >= NTc * EMBc) return;
    int nt = i / EMBc, e = i - nt * EMBc;
    int id = atoms[nt];
    float v = ew[id * EMBc + e] * (float)id;
    unsigned short h, l; split2(v, h, l);
    shi[nt * H1c + e] = h;
    slo[nt * H1c + e] = l;
}

// ---------------- LSTM1 scan (unchanged from Round 1)
template <int KIN>
__global__ void __launch_bounds__(256)
k_scan1(unsigned short* seq_hi, unsigned short* seq_lo,
        const unsigned short* __restrict__ Whi, const unsigned short* __restrict__ Wlo,
        const float* __restrict__ bptr, float* __restrict__ dacc,
        int accum, int writeSeq)
{
    constexpr int KTOT = KIN + 64;
    constexpr int KCH  = KTOT / 32;
    constexpr int SX   = KTOT + 8;
    __shared__ alignas(16) unsigned short xh_hi[32 * SX];
    __shared__ alignas(16) unsigned short xh_lo[32 * SX];

    const int tid  = threadIdx.x;
    const int lane = tid & 63;
    const int wv   = tid >> 6;
    const int l16  = lane & 15;
    const int quad = lane >> 4;
    const int n0   = blockIdx.x * 32;
    const int d    = wv * 16 + l16;

    float bias[4];
#pragma unroll
    for (int g = 0; g < 4; ++g) bias[g] = bptr[g * 64 + d];

    bf16x8 wbh[KCH][4], wbl[KCH][4];
#pragma unroll
    for (int kc = 0; kc < KCH; ++kc) {
        const int kb = kc * 32 + quad * 8;
#pragma unroll
        for (int g = 0; g < 4; ++g) {
            const int j = g * 64 + d;
            wbh[kc][g] = *(const bf16x8*)&Whi[j * 128 + kb];
            wbl[kc][g] = *(const bf16x8*)&Wlo[j * 128 + kb];
        }
    }

    f32x4 c[2];
    c[0] = {1.f, 1.f, 1.f, 1.f};
    c[1] = {1.f, 1.f, 1.f, 1.f};

#pragma unroll
    for (int mt = 0; mt < 2; ++mt)
#pragma unroll
        for (int r = 0; r < 4; ++r) {
            int s = mt * 16 + quad * 4 + r;
            xh_hi[s * SX + KIN + d] = 0x3F80;
            xh_lo[s * SX + KIN + d] = 0;
        }

#pragma unroll 1
    for (int t = 0; t < T1c; ++t) {
        for (int idx = tid; idx < 32 * KIN; idx += 256) {
            int s = idx / KIN, k = idx - s * KIN;
            int row = (n0 + s) * T1c + t;
            xh_hi[s * SX + k] = seq_hi[row * H1c + k];
            xh_lo[s * SX + k] = seq_lo[row * H1c + k];
        }
        __syncthreads();

        f32x4 acc[2][4];
#pragma unroll
        for (int mt = 0; mt < 2; ++mt)
#pragma unroll
            for (int g = 0; g < 4; ++g)
                acc[mt][g] = {bias[g], bias[g], bias[g], bias[g]};

#pragma unroll
        for (int kc = 0; kc < KCH; ++kc) {
            const int kb = kc * 32 + quad * 8;
            bf16x8 ah[2], al[2];
#pragma unroll
            for (int mt = 0; mt < 2; ++mt) {
                const int ro = (mt * 16 + l16) * SX + kb;
                ah[mt] = *(const bf16x8*)&xh_hi[ro];
                al[mt] = *(const bf16x8*)&xh_lo[ro];
            }
#pragma unroll
            for (int g = 0; g < 4; ++g)
#pragma unroll
                for (int mt = 0; mt < 2; ++mt) {
                    acc[mt][g] = __builtin_amdgcn_mfma_f32_16x16x32_bf16(ah[mt], wbh[kc][g], acc[mt][g], 0, 0, 0);
                    acc[mt][g] = __builtin_amdgcn_mfma_f32_16x16x32_bf16(ah[mt], wbl[kc][g], acc[mt][g], 0, 0, 0);
                    acc[mt][g] = __builtin_amdgcn_mfma_f32_16x16x32_bf16(al[mt], wbh[kc][g], acc[mt][g], 0, 0, 0);
                }
        }
        __syncthreads();

#pragma unroll
        for (int mt = 0; mt < 2; ++mt)
#pragma unroll
            for (int r = 0; r < 4; ++r) {
                float iv = sigm(acc[mt][0][r]);
                float fv = sigm(acc[mt][1][r]);
                float gv = tanhf_(acc[mt][2][r]);
                float ov = sigm(acc[mt][3][r]);
                float cv = fv * c[mt][r] + iv * gv;
                c[mt][r] = cv;
                float hv = ov * tanhf_(cv);
                unsigned short hh, hl; split2(hv, hh, hl);
                int s = mt * 16 + quad * 4 + r;
                xh_hi[s * SX + KIN + d] = hh;
                xh_lo[s * SX + KIN + d] = hl;
                if (writeSeq) {
                    int row = (n0 + s) * T1c + t;
                    seq_hi[row * H1c + d] = hh;
                    seq_lo[row * H1c + d] = hl;
                }
                if (t == T1c - 1) {
                    int o = (n0 + s) * H1c + d;
                    float val = 0.25f * (hv + cv);
                    if (accum) dacc[o] += val; else dacc[o] = val;
                }
            }
    }
}

// ---------------- BN2 stats (unchanged)
__global__ void __launch_bounds__(256)
k_bn2_stats(const int* __restrict__ lens, const float* __restrict__ dacc,
            float* __restrict__ stats)
{
    int b = blockIdx.x;
    int off = 0;
    for (int i = 0; i < b; ++i) off += lens[i];
    int len = lens[b];
    const float* base = dacc + (long)off * H1c;
    float s = 0.f, ss = 0.f;
    int total = len * H1c;
    for (int i = threadIdx.x; i < total; i += 256) { float v = base[i]; s += v; ss += v * v; }
    __shared__ float rs[256], rss[256];
    rs[threadIdx.x] = s; rss[threadIdx.x] = ss;
    __syncthreads();
    for (int st = 128; st > 0; st >>= 1) {
        if (threadIdx.x < st) { rs[threadIdx.x] += rs[threadIdx.x + st]; rss[threadIdx.x] += rss[threadIdx.x + st]; }
        __syncthreads();
    }
    if (threadIdx.x == 0) {
        float m = rs[0] / (float)(LMAXc * H1c);
        float v = rss[0] / (float)(LMAXc * H1c) - m * m;
        stats[b]      = m;
        stats[32 + b] = rsqrtf(fmaxf(v, 0.f) + EPSc);
        stats[64 + b] = (float)off;
    }
}

// ---------------- BN2 apply -> LSTM2 layer-0 input, packed u32, t-major rows (t*32+b)
__global__ void __launch_bounds__(256)
k_bn2_apply(const float* __restrict__ dacc, const float* __restrict__ stats,
            const int* __restrict__ lens, const float* __restrict__ g,
            const float* __restrict__ bb, unsigned int* __restrict__ outP)
{
    int i = blockIdx.x * 256 + threadIdx.x;
    if (i >= R2c * H1c) return;
    int rr = i / H1c, k = i - rr * H1c;
    int b = rr >> 10, p = rr & 1023;
    int off = (int)stats[64 + b];
    float x = (p < lens[b]) ? dacc[(off + p) * H1c + k] : 0.f;
    float y = (x - stats[b]) * stats[32 + b] * g[b] + bb[b];
    outP[(p * 32 + b) * H1c + k] = packbf(y);
}

// ---------------- xg GEMM for LSTM2. Rows are t-major (rr = t*32+b); one WG per
// timestep.  Output permuted: xg[rr*512 + d*4 + g]  (g = wave id 0..3).
template <int KIN2>
__global__ void __launch_bounds__(256)
k_xg2(const unsigned int* __restrict__ inP,
      const unsigned short* __restrict__ Whi, const unsigned short* __restrict__ Wlo,
      const float* __restrict__ bias, float* __restrict__ xg)
{
    constexpr int SX  = KIN2 + 8;
    constexpr int KCH = KIN2 / 32;
    __shared__ alignas(16) unsigned short a_hi[32 * SX];
    __shared__ alignas(16) unsigned short a_lo[32 * SX];
    const int tid = threadIdx.x, lane = tid & 63, wv = tid >> 6;
    const int l16 = lane & 15, quad = lane >> 4;
    const int r0 = blockIdx.x * 32;

    for (int idx = tid; idx < 32 * KIN2; idx += 256) {
        int s = idx / KIN2, k = idx - s * KIN2;
        unsigned u = inP[(r0 + s) * KIN2 + k];
        a_hi[s * SX + k] = (unsigned short)(u & 0xffffu);
        a_lo[s * SX + k] = (unsigned short)(u >> 16);
    }
    __syncthreads();

    f32x4 acc[2][8];
#pragma unroll
    for (int mt = 0; mt < 2; ++mt)
#pragma unroll
        for (int nt = 0; nt < 8; ++nt) {
            float bv = bias[wv * 128 + nt * 16 + l16];
            acc[mt][nt] = {bv, bv, bv, bv};
        }

#pragma unroll
    for (int kc = 0; kc < KCH; ++kc) {
        const int kb = kc * 32 + quad * 8;
        bf16x8 ah[2], al[2];
#pragma unroll
        for (int mt = 0; mt < 2; ++mt) {
            const int ro = (mt * 16 + l16) * SX + kb;
            ah[mt] = *(const bf16x8*)&a_hi[ro];
            al[mt] = *(const bf16x8*)&a_lo[ro];
        }
#pragma unroll
        for (int nt = 0; nt < 8; ++nt) {
            const int j = wv * 128 + nt * 16 + l16;
            bf16x8 bh = *(const bf16x8*)&Whi[j * 128 + kb];
            bf16x8 bl = *(const bf16x8*)&Wlo[j * 128 + kb];
#pragma unroll
            for (int mt = 0; mt < 2; ++mt) {
                acc[mt][nt] = __builtin_amdgcn_mfma_f32_16x16x32_bf16(ah[mt], bh, acc[mt][nt], 0, 0, 0);
                acc[mt][nt] = __builtin_amdgcn_mfma_f32_16x16x32_bf16(ah[mt], bl, acc[mt][nt], 0, 0, 0);
                acc[mt][nt] = __builtin_amdgcn_mfma_f32_16x16x32_bf16(al[mt], bh, acc[mt][nt], 0, 0, 0);
            }
        }
    }
#pragma unroll
    for (int mt = 0; mt < 2; ++mt)
#pragma unroll
        for (int nt = 0; nt < 8; ++nt)
#pragma unroll
            for (int r = 0; r < 4; ++r) {
                int rr = r0 + mt * 16 + quad * 4 + r;   // = t*32 + b
                int dd = nt * 16 + l16;
                xg[rr * 512 + dd * 4 + wv] = acc[mt][nt][r];
            }
}

// ---------------- LSTM2 scan: 1 WG, 8 waves.  xg prefetched (reg double-buffer,
// float4); ping-pong LDS h -> one barrier/step; packed u32 seq stores.
__global__ void __launch_bounds__(512, 2)
k_scan2(const float* __restrict__ xg, const unsigned short* __restrict__ Whi,
        const unsigned short* __restrict__ Wlo,
        unsigned int* __restrict__ seqP,
        float* __restrict__ c2acc, int accum, int writeSeq)
{
    constexpr int SH = H2c + 8;                    // 136 (16B-aligned rows)
    __shared__ alignas(16) unsigned short hh[2][32 * SH];
    __shared__ alignas(16) unsigned short hl[2][32 * SH];
    const int tid = threadIdx.x, lane = tid & 63, wv = tid >> 6;  // wv = 0..7
    const int l16 = lane & 15, quad = lane >> 4;
    const int d = wv * 16 + l16;

    bf16x8 wbh[4][4], wbl[4][4];
#pragma unroll
    for (int kc = 0; kc < 4; ++kc) {
        const int kb = kc * 32 + quad * 8;
#pragma unroll
        for (int g = 0; g < 4; ++g) {
            const int j = g * 128 + d;
            wbh[kc][g] = *(const bf16x8*)&Whi[j * 128 + kb];
            wbl[kc][g] = *(const bf16x8*)&Wlo[j * 128 + kb];
        }
    }

    f32x4 c[2];
    c[0] = {1.f, 1.f, 1.f, 1.f};
    c[1] = {1.f, 1.f, 1.f, 1.f};
#pragma unroll
    for (int mt = 0; mt < 2; ++mt)
#pragma unroll
        for (int r = 0; r < 4; ++r) {
            int s = mt * 16 + quad * 4 + r;
            hh[0][s * SH + d] = 0x3F80;            // bf16(1.0)
            hl[0][s * SH + d] = 0;
        }
    __syncthreads();

    const f32x4* xg4 = (const f32x4*)xg;           // index: rr*128 + d
    f32x4 xcur[2][4];
#pragma unroll
    for (int mt = 0; mt < 2; ++mt)
#pragma unroll
        for (int r = 0; r < 4; ++r) {
            int sr = mt * 16 + quad * 4 + r;
            xcur[mt][r] = xg4[sr * 128 + d];
        }

#pragma unroll 1
    for (int t = 0; t < LMAXc; ++t) {
        // prefetch xg(t+1) — consumed only after this step's barrier
        f32x4 xnxt[2][4];
        const int tn = (t + 1 < LMAXc) ? t + 1 : t;
#pragma unroll
        for (int mt = 0; mt < 2; ++mt)
#pragma unroll
            for (int r = 0; r < 4; ++r) {
                int sr = mt * 16 + quad * 4 + r;
                xnxt[mt][r] = xg4[(tn * 32 + sr) * 128 + d];
            }

        const int p = t & 1;
        f32x4 acc[2][4];
#pragma unroll
        for (int mt = 0; mt < 2; ++mt)
#pragma unroll
            for (int g = 0; g < 4; ++g)
#pragma unroll
                for (int r = 0; r < 4; ++r)
                    acc[mt][g][r] = xcur[mt][r][g];

#pragma unroll
        for (int kc = 0; kc < 4; ++kc) {
            const int kb = kc * 32 + quad * 8;
            bf16x8 ah[2], al[2];
#pragma unroll
            for (int mt = 0; mt < 2; ++mt) {
                const int ro = (mt * 16 + l16) * SH + kb;
                ah[mt] = *(const bf16x8*)&hh[p][ro];
                al[mt] = *(const bf16x8*)&hl[p][ro];
            }
#pragma unroll
            for (int g = 0; g < 4; ++g)
#pragma unroll
                for (int mt = 0; mt < 2; ++mt) {
                    acc[mt][g] = __builtin_amdgcn_mfma_f32_16x16x32_bf16(ah[mt], wbh[kc][g], acc[mt][g], 0, 0, 0);
                    acc[mt][g] = __builtin_amdgcn_mfma_f32_16x16x32_bf16(ah[mt], wbl[kc][g], acc[mt][g], 0, 0, 0);
                    acc[mt][g] = __builtin_amdgcn_mfma_f32_16x16x32_bf16(al[mt], wbh[kc][g], acc[mt][g], 0, 0, 0);
                }
        }

        // epilogue: writes go to buffer p^1 (no conflict with this step's reads)
#pragma unroll
        for (int mt = 0; mt < 2; ++mt)
#pragma unroll
            for (int r = 0; r < 4; ++r) {
                float iv = sigm(acc[mt][0][r]);
                float fv = sigm(acc[mt][1][r]);
                float gv = tanhf_(acc[mt][2][r]);
                float ov = sigm(acc[mt][3][r]);
                float cv = fv * c[mt][r] + iv * gv;
                c[mt][r] = cv;
                float hv = ov * tanhf_(cv);
                unsigned short hbh, hbl; split2(hv, hbh, hbl);
                const int sr = mt * 16 + quad * 4 + r;
                hh[p ^ 1][sr * SH + d] = hbh;
                hl[p ^ 1][sr * SH + d] = hbl;
                if (writeSeq)
                    seqP[(t * 32 + sr) * H2c + d] = (unsigned)hbh | ((unsigned)hbl << 16);
                if (t == LMAXc - 1) {
                    int o = sr * H2c + d;
                    float val = 0.25f * cv;
                    if (accum) c2acc[o] += val; else c2acc[o] = val;
                }
            }
        __syncthreads();
#pragma unroll
        for (int mt = 0; mt < 2; ++mt)
#pragma unroll
            for (int r = 0; r < 4; ++r)
                xcur[mt][r] = xnxt[mt][r];
    }
}

// ---------------- head: BN3 + MLP + relu(sum), single WG fp32 (unchanged)
DEVI void bn_rows_dev(float* X, int K, const float* g, const float* bb,
                      float* mv, int tid)
{
    __syncthreads();
    if (tid < 32) {
        float s = 0.f, ss = 0.f;
        const float* r = X + tid * K;
        for (int k = 0; k < K; ++k) { float v = r[k]; s += v; ss += v * v; }
        float m = s / (float)K;
        float vv = ss / (float)K - m * m;
        mv[tid]      = m;
        mv[32 + tid] = rsqrtf(fmaxf(vv, 0.f) + EPSc);
    }
    __syncthreads();
    for (int i = tid; i < 32 * K; i += 256) {
        int b = i / K;
        X[i] = (X[i] - mv[b]) * mv[32 + b] * g[b] + bb[b];
    }
    __syncthreads();
}

DEVI void lin_dev(const float* X, int K, const float* W, const float* bias,
                  int NO, float* Y, int relu, int tid)
{
    __syncthreads();
    for (int i = tid; i < 32 * NO; i += 256) {
        int b = i / NO, j = i - b * NO;
        float a = bias[j];
        const float* xr = X + b * K;
        const float* wr = W + j * K;
        for (int k = 0; k < K; ++k) a += xr[k] * wr[k];
        Y[i] = relu ? fmaxf(a, 0.f) : a;
    }
    __syncthreads();
}

__global__ void __launch_bounds__(256)
k_head(const float* __restrict__ c2, const float* __restrict__ g3, const float* __restrict__ bb3,
       const float* w1, const float* b1, const float* w2, const float* b2,
       const float* w22, const float* b22, const float* w3, const float* b3,
       const float* w4, const float* b4, const float* w5, const float* b5,
       float* __restrict__ out)
{
    __shared__ float A[32 * 128];
    __shared__ float Bf[32 * 128];
    __shared__ float mv[64];
    const int tid = threadIdx.x;

    for (int i = tid; i < 32 * 128; i += 256) A[i] = c2[i];
    bn_rows_dev(A, 128, g3, bb3, mv, tid);
    lin_dev(A, 128, w1, b1, 128, Bf, 1, tid);
    lin_dev(Bf, 128, w2, b2, 64, A, 1, tid);
    bn_rows_dev(A, 64, g3, bb3, mv, tid);
    lin_dev(A, 64, w22, b22, 64, Bf, 1, tid);
    lin_dev(Bf, 64, w3, b3, 32, A, 1, tid);
    lin_dev(A, 32, w4, b4, 32, Bf, 1, tid);
    lin_dev(Bf, 32, w5, b5, 16, A, 0, tid);
    if (tid < 32) {
        float s = 0.f;
        for (int j = 0; j < 16; ++j) s += A[tid * 16 + j];
        out[tid] = fmaxf(s, 0.f);
    }
}

// ---------------- host
extern "C" void kernel_launch(void* const* d_in, const int* in_sizes, int n_in,
                              void* d_out, int out_size, void* d_ws, size_t ws_size,
                              hipStream_t stream)
{
    const int*   atoms  = (const int*)d_in[0];
    const int*   lens   = (const int*)d_in[2];
    const float* embw   = (const float*)d_in[5];
    const float* l1Wih0 = (const float*)d_in[6];
    const float* l1Whh0 = (const float*)d_in[7];
    const float* l1b0   = (const float*)d_in[8];
    const float* l1Wih  = (const float*)d_in[9];
    const float* l1Whh  = (const float*)d_in[10];
    const float* l1b    = (const float*)d_in[11];
    const float* l2Wih0 = (const float*)d_in[12];
    const float* l2Whh0 = (const float*)d_in[13];
    const float* l2b0   = (const float*)d_in[14];
    const float* l2Wih  = (const float*)d_in[15];
    const float* l2Whh  = (const float*)d_in[16];
    const float* l2b    = (const float*)d_in[17];
    const float* bn2g   = (const float*)d_in[18];
    const float* bn2b   = (const float*)d_in[19];
    const float* bn3g   = (const float*)d_in[20];
    const float* bn3b   = (const float*)d_in[21];
    const float* w1  = (const float*)d_in[22]; const float* b1  = (const float*)d_in[23];
    const float* w2  = (const float*)d_in[24]; const float* b2  = (const float*)d_in[25];
    const float* w22 = (const float*)d_in[26]; const float* b22 = (const float*)d_in[27];
    const float* w3  = (const float*)d_in[28]; const float* b3  = (const float*)d_in[29];
    const float* w4  = (const float*)d_in[30]; const float* b4  = (const float*)d_in[31];
    const float* w5  = (const float*)d_in[32]; const float* b5  = (const float*)d_in[33];
    float* out = (float*)d_out;

    char* base = (char*)d_ws;
    size_t off = 0;
    auto take = [&](size_t bytes) -> char* {
        char* p = base + off;
        off = (off + bytes + 255) & ~(size_t)255;
        return p;
    };
    unsigned short* seq1h = (unsigned short*)take((size_t)NTc * H1c * 2);   // 63.6 MB
    unsigned short* seq1l = (unsigned short*)take((size_t)NTc * H1c * 2);
    float*          dacc  = (float*)take((size_t)Ntot * H1c * 4);           // 6.4 MB
    unsigned short* w1h   = (unsigned short*)take((size_t)4 * 256 * 128 * 2);
    unsigned short* w1l   = (unsigned short*)take((size_t)4 * 256 * 128 * 2);
    unsigned short* whhh  = (unsigned short*)take((size_t)4 * 512 * 128 * 2);
    unsigned short* whhl  = (unsigned short*)take((size_t)4 * 512 * 128 * 2);
    unsigned short* wihh  = (unsigned short*)take((size_t)4 * 512 * 128 * 2);
    unsigned short* wihl  = (unsigned short*)take((size_t)4 * 512 * 128 * 2);
    unsigned int*   seqA  = (unsigned int*)take((size_t)R2c * H1c * 4);     // 8.4 MB (layer-0 in)
    unsigned int*   seqB  = (unsigned int*)take((size_t)R2c * H2c * 4);     // 16.8 MB (h between layers)
    float*          xg2   = (float*)take((size_t)R2c * 512 * 4);            // 67 MB
    float*          stats = (float*)take(1024);
    float*          c2    = (float*)take((size_t)32 * 128 * 4);

    auto prep = [&](const float* src, unsigned short* dh, unsigned short* dl,
                    int R, int K, int OS, int KO) {
        int n = R * K;
        k_prep<<<(n + 255) / 256, 256, 0, stream>>>(src, dh, dl, R, K, OS, KO);
    };

    prep(l1Wih0, w1h, w1l, 256, 32, 128, 0);
    prep(l1Whh0, w1h, w1l, 256, 64, 128, 32);
    for (int l = 1; l < 4; ++l) {
        prep(l1Wih + (l - 1) * 256 * 64, w1h + l * 256 * 128, w1l + l * 256 * 128, 256, 64, 128, 0);
        prep(l1Whh + (l - 1) * 256 * 64, w1h + l * 256 * 128, w1l + l * 256 * 128, 256, 64, 128, 64);
    }
    prep(l2Whh0, whhh, whhl, 512, 128, 128, 0);
    for (int l = 1; l < 4; ++l)
        prep(l2Whh + (l - 1) * 512 * 128, whhh + l * 512 * 128, whhl + l * 512 * 128, 512, 128, 128, 0);
    prep(l2Wih0, wihh, wihl, 512, 64, 128, 0);
    for (int l = 1; l < 4; ++l)
        prep(l2Wih + (l - 1) * 512 * 128, wihh + l * 512 * 128, wihl + l * 512 * 128, 512, 128, 128, 0);

    k_embed<<<(NTc * EMBc + 255) / 256, 256, 0, stream>>>(atoms, embw, seq1h, seq1l);

    for (int l = 0; l < 4; ++l) {
        const float* bp = (l == 0) ? l1b0 : l1b + (l - 1) * 256;
        if (l == 0)
            k_scan1<32><<<Ntot / 32, 256, 0, stream>>>(seq1h, seq1l, w1h, w1l, bp, dacc, 0, 1);
        else
            k_scan1<64><<<Ntot / 32, 256, 0, stream>>>(seq1h, seq1l,
                                                       w1h + l * 256 * 128, w1l + l * 256 * 128,
                                                       bp, dacc, 1, (l != 3) ? 1 : 0);
    }

    k_bn2_stats<<<32, 256, 0, stream>>>(lens, dacc, stats);
    k_bn2_apply<<<(R2c * H1c + 255) / 256, 256, 0, stream>>>(dacc, stats, lens, bn2g, bn2b, seqA);

    for (int l = 0; l < 4; ++l) {
        const float* bp = (l == 0) ? l2b0 : l2b + (l - 1) * 512;
        if (l == 0)
            k_xg2<64><<<R2c / 32, 256, 0, stream>>>(seqA, wihh, wihl, bp, xg2);
        else
            k_xg2<128><<<R2c / 32, 256, 0, stream>>>(seqB,
                                                     wihh + l * 512 * 128, wihl + l * 512 * 128, bp, xg2);
        k_scan2<<<1, 512, 0, stream>>>(xg2, whhh + l * 512 * 128, whhl + l * 512 * 128,
                                       seqB, c2, (l != 0) ? 1 : 0, (l != 3) ? 1 : 0);
    }

    k_head<<<1, 256, 0, stream>>>(c2, bn3g, bn3b, w1, b1, w2, b2, w22, b22,
                                  w3, b3, w4, b4, w5, b5, out);

    (void)in_sizes; (void)n_in; (void)out_size; (void)ws_size;
}

// Round 3
// 8183.361 us; speedup vs baseline: 2.7545x; 2.5596x over previous
//
#include <hip/hip_runtime.h>

// Round 3: LSTM2 restructured as a 4-stage producer/consumer pipeline.
//  - ONE kernel, grid=4: WG l runs layer l; flag-based handoff (threadfence +
//    agent-scope atomics). Steady-state = 1 layer's step cost, not 4.
//  - fp16 single-term MFMA in LSTM2 (fp32 accum/state): 64 MFMA/wave/step
//    (vs 96 3-term hidden-only), tiny epilogue (cvt_f16 instead of split2).
//  - input GEMM fused into the scan: x fragments loaded straight from the
//    producer's published h (global), no xg buffer/kernels.
// LSTM1 unchanged (split-bf16 3-term, 776 WGs).

typedef short    bf16x8 __attribute__((ext_vector_type(8)));
typedef _Float16 f16x8  __attribute__((ext_vector_type(8)));
typedef float    f32x4  __attribute__((ext_vector_type(4)));

#define DEVI static __device__ __forceinline__

constexpr int   T1c   = 20;
constexpr int   EMBc  = 32;
constexpr int   H1c   = 64;
constexpr int   H2c   = 128;
constexpr int   LMAXc = 1024;
constexpr int   Ntot  = 24832;           // sum of lengths
constexpr int   NTc   = Ntot * T1c;      // 496640
constexpr int   R2c   = 32 * LMAXc;      // 32768
constexpr float EPSc  = 1e-5f;

DEVI unsigned short f2bf(float x) {      // RNE float->bf16
    unsigned u = __float_as_uint(x);
    u += 0x7FFFu + ((u >> 16) & 1u);
    return (unsigned short)(u >> 16);
}
DEVI float bf2f(unsigned short h) { return __uint_as_float((unsigned)h << 16); }
DEVI void split2(float x, unsigned short &hi, unsigned short &lo) {
    hi = f2bf(x);
    lo = f2bf(x - bf2f(hi));
}
DEVI float sigm(float x)   { return 1.f / (1.f + __expf(-x)); }
DEVI float tanhf_(float x) { return 1.f - 2.f / (1.f + __expf(2.f * x)); }

// ---------------- weight prep: f32 -> (hi,lo) bf16 (LSTM1)
__global__ void __launch_bounds__(256)
k_prep(const float* __restrict__ in, unsigned short* __restrict__ hi,
       unsigned short* __restrict__ lo, int R, int K, int OS, int KO)
{
    int i = blockIdx.x * 256 + threadIdx.x;
    if (i >= R * K) return;
    int r = i / K, k = i - r * K;
    unsigned short h, l; split2(in[i], h, l);
    hi[r * OS + KO + k] = h;
    lo[r * OS + KO + k] = l;
}

// ---------------- weight prep: f32 -> fp16, elementwise (LSTM2)
__global__ void __launch_bounds__(256)
k_prep16(const float* __restrict__ in, _Float16* __restrict__ out, int n)
{
    int i = blockIdx.x * 256 + threadIdx.x;
    if (i < n) out[i] = (_Float16)in[i];
}

// ---------------- embedding: x = embed_w[id] * id, split into seq1 (row stride 64)
__global__ void __launch_bounds__(256)
k_embed(const int* __restrict__ atoms, const float* __restrict__ ew,
        unsigned short* __restrict__ shi, unsigned short* __restrict__ slo)
{
    int i = blockIdx.x * 256 + threadIdx.x;
    if (i >= NTc * EMBc) return;
    int nt = i / EMBc, e = i - nt * EMBc;
    int id = atoms[nt];
    float v = ew[id * EMBc + e] * (float)id;
    unsigned short h, l; split2(v, h, l);
    shi[nt * H1c + e] = h;
    slo[nt * H1c + e] = l;
}

// ---------------- LSTM1 scan (unchanged from Round 2)
template <int KIN>
__global__ void __launch_bounds__(256)
k_scan1(unsigned short* seq_hi, unsigned short* seq_lo,
        const unsigned short* __restrict__ Whi, const unsigned short* __restrict__ Wlo,
        const float* __restrict__ bptr, float* __restrict__ dacc,
        int accum, int writeSeq)
{
    constexpr int KTOT = KIN + 64;
    constexpr int KCH  = KTOT / 32;
    constexpr int SX   = KTOT + 8;
    __shared__ alignas(16) unsigned short xh_hi[32 * SX];
    __shared__ alignas(16) unsigned short xh_lo[32 * SX];

    const int tid  = threadIdx.x;
    const int lane = tid & 63;
    const int wv   = tid >> 6;
    const int l16  = lane & 15;
    const int quad = lane >> 4;
    const int n0   = blockIdx.x * 32;
    const int d    = wv * 16 + l16;

    float bias[4];
#pragma unroll
    for (int g = 0; g < 4; ++g) bias[g] = bptr[g * 64 + d];

    bf16x8 wbh[KCH][4], wbl[KCH][4];
#pragma unroll
    for (int kc = 0; kc < KCH; ++kc) {
        const int kb = kc * 32 + quad * 8;
#pragma unroll
        for (int g = 0; g < 4; ++g) {
            const int j = g * 64 + d;
            wbh[kc][g] = *(const bf16x8*)&Whi[j * 128 + kb];
            wbl[kc][g] = *(const bf16x8*)&Wlo[j * 128 + kb];
        }
    }

    f32x4 c[2];
    c[0] = {1.f, 1.f, 1.f, 1.f};
    c[1] = {1.f, 1.f, 1.f, 1.f};

#pragma unroll
    for (int mt = 0; mt < 2; ++mt)
#pragma unroll
        for (int r = 0; r < 4; ++r) {
            int s = mt * 16 + quad * 4 + r;
            xh_hi[s * SX + KIN + d] = 0x3F80;
            xh_lo[s * SX + KIN + d] = 0;
        }

#pragma unroll 1
    for (int t = 0; t < T1c; ++t) {
        for (int idx = tid; idx < 32 * KIN; idx += 256) {
            int s = idx / KIN, k = idx - s * KIN;
            int row = (n0 + s) * T1c + t;
            xh_hi[s * SX + k] = seq_hi[row * H1c + k];
            xh_lo[s * SX + k] = seq_lo[row * H1c + k];
        }
        __syncthreads();

        f32x4 acc[2][4];
#pragma unroll
        for (int mt = 0; mt < 2; ++mt)
#pragma unroll
            for (int g = 0; g < 4; ++g)
                acc[mt][g] = {bias[g], bias[g], bias[g], bias[g]};

#pragma unroll
        for (int kc = 0; kc < KCH; ++kc) {
            const int kb = kc * 32 + quad * 8;
            bf16x8 ah[2], al[2];
#pragma unroll
            for (int mt = 0; mt < 2; ++mt) {
                const int ro = (mt * 16 + l16) * SX + kb;
                ah[mt] = *(const bf16x8*)&xh_hi[ro];
                al[mt] = *(const bf16x8*)&xh_lo[ro];
            }
#pragma unroll
            for (int g = 0; g < 4; ++g)
#pragma unroll
                for (int mt = 0; mt < 2; ++mt) {
                    acc[mt][g] = __builtin_amdgcn_mfma_f32_16x16x32_bf16(ah[mt], wbh[kc][g], acc[mt][g], 0, 0, 0);
                    acc[mt][g] = __builtin_amdgcn_mfma_f32_16x16x32_bf16(ah[mt], wbl[kc][g], acc[mt][g], 0, 0, 0);
                    acc[mt][g] = __builtin_amdgcn_mfma_f32_16x16x32_bf16(al[mt], wbh[kc][g], acc[mt][g], 0, 0, 0);
                }
        }
        __syncthreads();

#pragma unroll
        for (int mt = 0; mt < 2; ++mt)
#pragma unroll
            for (int r = 0; r < 4; ++r) {
                float iv = sigm(acc[mt][0][r]);
                float fv = sigm(acc[mt][1][r]);
                float gv = tanhf_(acc[mt][2][r]);
                float ov = sigm(acc[mt][3][r]);
                float cv = fv * c[mt][r] + iv * gv;
                c[mt][r] = cv;
                float hv = ov * tanhf_(cv);
                unsigned short hh, hl; split2(hv, hh, hl);
                int s = mt * 16 + quad * 4 + r;
                xh_hi[s * SX + KIN + d] = hh;
                xh_lo[s * SX + KIN + d] = hl;
                if (writeSeq) {
                    int row = (n0 + s) * T1c + t;
                    seq_hi[row * H1c + d] = hh;
                    seq_lo[row * H1c + d] = hl;
                }
                if (t == T1c - 1) {
                    int o = (n0 + s) * H1c + d;
                    float val = 0.25f * (hv + cv);
                    if (accum) dacc[o] += val; else dacc[o] = val;
                }
            }
    }
}

// ---------------- BN2 stats (unchanged)
__global__ void __launch_bounds__(256)
k_bn2_stats(const int* __restrict__ lens, const float* __restrict__ dacc,
            float* __restrict__ stats)
{
    int b = blockIdx.x;
    int off = 0;
    for (int i = 0; i < b; ++i) off += lens[i];
    int len = lens[b];
    const float* base = dacc + (long)off * H1c;
    float s = 0.f, ss = 0.f;
    int total = len * H1c;
    for (int i = threadIdx.x; i < total; i += 256) { float v = base[i]; s += v; ss += v * v; }
    __shared__ float rs[256], rss[256];
    rs[threadIdx.x] = s; rss[threadIdx.x] = ss;
    __syncthreads();
    for (int st = 128; st > 0; st >>= 1) {
        if (threadIdx.x < st) { rs[threadIdx.x] += rs[threadIdx.x + st]; rss[threadIdx.x] += rss[threadIdx.x + st]; }
        __syncthreads();
    }
    if (threadIdx.x == 0) {
        float m = rs[0] / (float)(LMAXc * H1c);
        float v = rss[0] / (float)(LMAXc * H1c) - m * m;
        stats[b]      = m;
        stats[32 + b] = rsqrtf(fmaxf(v, 0.f) + EPSc);
        stats[64 + b] = (float)off;
    }
}

// ---------------- BN2 apply -> LSTM2 layer-0 input, fp16, t-major rows (t*32+b)
__global__ void __launch_bounds__(256)
k_bn2_apply(const float* __restrict__ dacc, const float* __restrict__ stats,
            const int* __restrict__ lens, const float* __restrict__ g,
            const float* __restrict__ bb, _Float16* __restrict__ outA)
{
    int i = blockIdx.x * 256 + threadIdx.x;
    if (i >= R2c * H1c) return;
    int rr = i / H1c, k = i - rr * H1c;
    int b = rr >> 10, p = rr & 1023;
    int off = (int)stats[64 + b];
    float x = (p < lens[b]) ? dacc[(off + p) * H1c + k] : 0.f;
    float y = (x - stats[b]) * stats[32 + b] * g[b] + bb[b];
    outA[(p * 32 + b) * H1c + k] = (_Float16)y;
}

// ---------------- LSTM2 pipelined scan body (one WG = one layer).
// 512 thr = 8 waves; wave wv owns gate-col slice d = wv*16+l16, gates via g-loop.
// x_t A-fragments loaded straight from producer's published h (global).
template <int KIN, bool HASIN, bool HASOUT>
DEVI void scan2_body(const _Float16* __restrict__ xsrc,   // rows (t*32+s)*KIN
                     _Float16* __restrict__ pub,          // rows (t*32+s)*128
                     const _Float16* __restrict__ Whh,    // [512][128]
                     const _Float16* __restrict__ Wih,    // [512][KIN]
                     const float* __restrict__ bias512,
                     float* __restrict__ c2out,
                     unsigned int* flagIn, unsigned int* flagOut)
{
    constexpr int KCI = KIN / 32;
    constexpr int SH  = H2c + 8;                  // 136 halves/row
    __shared__ alignas(16) _Float16 hbuf[2][32 * SH];

    const int tid  = threadIdx.x, lane = tid & 63, wv = tid >> 6;
    const int l16  = lane & 15, quad = lane >> 4;
    const int d    = wv * 16 + l16;

    float bias[4];
#pragma unroll
    for (int g = 0; g < 4; ++g) bias[g] = bias512[g * 128 + d];

    // register-resident weight B-fragments
    f16x8 whF[4][4], wiF[KCI][4];
#pragma unroll
    for (int kc = 0; kc < 4; ++kc) {
        const int kb = kc * 32 + quad * 8;
#pragma unroll
        for (int g = 0; g < 4; ++g)
            whF[kc][g] = *(const f16x8*)&Whh[(g * 128 + d) * 128 + kb];
    }
#pragma unroll
    for (int kc = 0; kc < KCI; ++kc) {
        const int kb = kc * 32 + quad * 8;
#pragma unroll
        for (int g = 0; g < 4; ++g)
            wiF[kc][g] = *(const f16x8*)&Wih[(g * 128 + d) * KIN + kb];
    }

    f32x4 c[2];
    c[0] = {1.f, 1.f, 1.f, 1.f};
    c[1] = {1.f, 1.f, 1.f, 1.f};
#pragma unroll
    for (int mt = 0; mt < 2; ++mt)
#pragma unroll
        for (int r = 0; r < 4; ++r) {
            int s = mt * 16 + quad * 4 + r;
            hbuf[0][s * SH + d] = (_Float16)1.0f;
        }
    __syncthreads();

#pragma unroll 1
    for (int t = 0; t < LMAXc; ++t) {
        if (HASIN) {
            const unsigned tgt = (unsigned)(t + 1);
            while (__hip_atomic_load(flagIn, __ATOMIC_RELAXED, __HIP_MEMORY_SCOPE_AGENT) < tgt)
                __builtin_amdgcn_s_sleep(2);
            __threadfence();                       // acquire: invalidate stale cache
        }
        // x_t A-fragments straight from global (latency hidden under hidden MFMAs)
        f16x8 xf[2][KCI];
#pragma unroll
        for (int mt = 0; mt < 2; ++mt)
#pragma unroll
            for (int kc = 0; kc < KCI; ++kc)
                xf[mt][kc] = *(const f16x8*)&xsrc[(size_t)(t * 32 + mt * 16 + l16) * KIN + kc * 32 + quad * 8];

        const int p = t & 1;
        f32x4 acc[2][4];
#pragma unroll
        for (int mt = 0; mt < 2; ++mt)
#pragma unroll
            for (int g = 0; g < 4; ++g)
                acc[mt][g] = {bias[g], bias[g], bias[g], bias[g]};

        // hidden path: h_{t-1} from LDS
#pragma unroll
        for (int kc = 0; kc < 4; ++kc) {
            const int kb = kc * 32 + quad * 8;
            f16x8 ah[2];
#pragma unroll
            for (int mt = 0; mt < 2; ++mt)
                ah[mt] = *(const f16x8*)&hbuf[p][(mt * 16 + l16) * SH + kb];
#pragma unroll
            for (int g = 0; g < 4; ++g)
#pragma unroll
                for (int mt = 0; mt < 2; ++mt)
                    acc[mt][g] = __builtin_amdgcn_mfma_f32_16x16x32_f16(ah[mt], whF[kc][g], acc[mt][g], 0, 0, 0);
        }
        // input path
#pragma unroll
        for (int kc = 0; kc < KCI; ++kc)
#pragma unroll
            for (int g = 0; g < 4; ++g)
#pragma unroll
                for (int mt = 0; mt < 2; ++mt)
                    acc[mt][g] = __builtin_amdgcn_mfma_f32_16x16x32_f16(xf[mt][kc], wiF[kc][g], acc[mt][g], 0, 0, 0);

        // epilogue
#pragma unroll
        for (int mt = 0; mt < 2; ++mt)
#pragma unroll
            for (int r = 0; r < 4; ++r) {
                float iv = sigm(acc[mt][0][r]);
                float fv = sigm(acc[mt][1][r]);
                float gv = tanhf_(acc[mt][2][r]);
                float ov = sigm(acc[mt][3][r]);
                float cv = fv * c[mt][r] + iv * gv;
                c[mt][r] = cv;
                float hv = ov * tanhf_(cv);
                _Float16 hf = (_Float16)hv;
                const int s = mt * 16 + quad * 4 + r;
                hbuf[p ^ 1][s * SH + d] = hf;
                if (HASOUT)
                    pub[(size_t)(t * 32 + s) * H2c + d] = hf;
                if (t == LMAXc - 1)
                    c2out[s * H2c + d] = 0.25f * cv;
            }
        __syncthreads();                           // drains vmcnt: publishes visible in L2
        if (HASOUT && tid == 0) {
            __threadfence();                       // release: writeback to coherence point
            __hip_atomic_store(flagOut, (unsigned)(t + 1), __ATOMIC_RELEASE, __HIP_MEMORY_SCOPE_AGENT);
        }
    }
}

__global__ void __launch_bounds__(512, 2)
k_scan2_pipe(const _Float16* __restrict__ seqA, _Float16* __restrict__ seqH,
             const _Float16* __restrict__ whh16, const _Float16* __restrict__ wih16,
             const float* __restrict__ b0, const float* __restrict__ bS,
             float* __restrict__ c2, unsigned int* __restrict__ flags)
{
    const int l = blockIdx.x;
    const _Float16* Whh = whh16 + (size_t)l * 512 * 128;
    const _Float16* Wih = wih16 + (size_t)l * 512 * 128;   // layer0: stride-64, 512*64 used
    const float*    bp  = (l == 0) ? b0 : bS + (l - 1) * 512;
    float*          c2o = c2 + l * 4096;
    _Float16*       pub = seqH + (size_t)l * R2c * H2c;    // unused by l==3
    const _Float16* xs  = (l == 0) ? seqA : seqH + (size_t)(l - 1) * R2c * H2c;

    if (l == 0)
        scan2_body<64,  false, true >(xs, pub, Whh, Wih, bp, c2o, nullptr,      flags + 0);
    else if (l == 3)
        scan2_body<128, true,  false>(xs, pub, Whh, Wih, bp, c2o, flags + 2,    nullptr);
    else if (l == 1)
        scan2_body<128, true,  true >(xs, pub, Whh, Wih, bp, c2o, flags + 0,    flags + 1);
    else
        scan2_body<128, true,  true >(xs, pub, Whh, Wih, bp, c2o, flags + 1,    flags + 2);
}

// ---------------- head: BN3 + MLP + relu(sum), single WG fp32
DEVI void bn_rows_dev(float* X, int K, const float* g, const float* bb,
                      float* mv, int tid)
{
    __syncthreads();
    if (tid < 32) {
        float s = 0.f, ss = 0.f;
        const float* r = X + tid * K;
        for (int k = 0; k < K; ++k) { float v = r[k]; s += v; ss += v * v; }
        float m = s / (float)K;
        float vv = ss / (float)K - m * m;
        mv[tid]      = m;
        mv[32 + tid] = rsqrtf(fmaxf(vv, 0.f) + EPSc);
    }
    __syncthreads();
    for (int i = tid; i < 32 * K; i += 256) {
        int b = i / K;
        X[i] = (X[i] - mv[b]) * mv[32 + b] * g[b] + bb[b];
    }
    __syncthreads();
}

DEVI void lin_dev(const float* X, int K, const float* W, const float* bias,
                  int NO, float* Y, int relu, int tid)
{
    __syncthreads();
    for (int i = tid; i < 32 * NO; i += 256) {
        int b = i / NO, j = i - b * NO;
        float a = bias[j];
        const float* xr = X + b * K;
        const float* wr = W + j * K;
        for (int k = 0; k < K; ++k) a += xr[k] * wr[k];
        Y[i] = relu ? fmaxf(a, 0.f) : a;
    }
    __syncthreads();
}

__global__ void __launch_bounds__(256)
k_head(const float* __restrict__ c2, const float* __restrict__ g3, const float* __restrict__ bb3,
       const float* w1, const float* b1, const float* w2, const float* b2,
       const float* w22, const float* b22, const float* w3, const float* b3,
       const float* w4, const float* b4, const float* w5, const float* b5,
       float* __restrict__ out)
{
    __shared__ float A[32 * 128];
    __shared__ float Bf[32 * 128];
    __shared__ float mv[64];
    const int tid = threadIdx.x;

    for (int i = tid; i < 32 * 128; i += 256)
        A[i] = c2[i] + c2[4096 + i] + c2[8192 + i] + c2[12288 + i];
    bn_rows_dev(A, 128, g3, bb3, mv, tid);
    lin_dev(A, 128, w1, b1, 128, Bf, 1, tid);
    lin_dev(Bf, 128, w2, b2, 64, A, 1, tid);
    bn_rows_dev(A, 64, g3, bb3, mv, tid);
    lin_dev(A, 64, w22, b22, 64, Bf, 1, tid);
    lin_dev(Bf, 64, w3, b3, 32, A, 1, tid);
    lin_dev(A, 32, w4, b4, 32, Bf, 1, tid);
    lin_dev(Bf, 32, w5, b5, 16, A, 0, tid);
    if (tid < 32) {
        float s = 0.f;
        for (int j = 0; j < 16; ++j) s += A[tid * 16 + j];
        out[tid] = fmaxf(s, 0.f);
    }
}

// ---------------- host
extern "C" void kernel_launch(void* const* d_in, const int* in_sizes, int n_in,
                              void* d_out, int out_size, void* d_ws, size_t ws_size,
                              hipStream_t stream)
{
    const int*   atoms  = (const int*)d_in[0];
    const int*   lens   = (const int*)d_in[2];
    const float* embw   = (const float*)d_in[5];
    const float* l1Wih0 = (const float*)d_in[6];
    const float* l1Whh0 = (const float*)d_in[7];
    const float* l1b0   = (const float*)d_in[8];
    const float* l1Wih  = (const float*)d_in[9];
    const float* l1Whh  = (const float*)d_in[10];
    const float* l1b    = (const float*)d_in[11];
    const float* l2Wih0 = (const float*)d_in[12];
    const float* l2Whh0 = (const float*)d_in[13];
    const float* l2b0   = (const float*)d_in[14];
    const float* l2Wih  = (const float*)d_in[15];
    const float* l2Whh  = (const float*)d_in[16];
    const float* l2b    = (const float*)d_in[17];
    const float* bn2g   = (const float*)d_in[18];
    const float* bn2b   = (const float*)d_in[19];
    const float* bn3g   = (const float*)d_in[20];
    const float* bn3b   = (const float*)d_in[21];
    const float* w1  = (const float*)d_in[22]; const float* b1  = (const float*)d_in[23];
    const float* w2  = (const float*)d_in[24]; const float* b2  = (const float*)d_in[25];
    const float* w22 = (const float*)d_in[26]; const float* b22 = (const float*)d_in[27];
    const float* w3  = (const float*)d_in[28]; const float* b3  = (const float*)d_in[29];
    const float* w4  = (const float*)d_in[30]; const float* b4  = (const float*)d_in[31];
    const float* w5  = (const float*)d_in[32]; const float* b5  = (const float*)d_in[33];
    float* out = (float*)d_out;

    char* base = (char*)d_ws;
    size_t off = 0;
    auto take = [&](size_t bytes) -> char* {
        char* p = base + off;
        off = (off + bytes + 255) & ~(size_t)255;
        return p;
    };
    unsigned short* seq1h  = (unsigned short*)take((size_t)NTc * H1c * 2);   // 63.6 MB
    unsigned short* seq1l  = (unsigned short*)take((size_t)NTc * H1c * 2);
    float*          dacc   = (float*)take((size_t)Ntot * H1c * 4);           // 6.4 MB
    unsigned short* w1h    = (unsigned short*)take((size_t)4 * 256 * 128 * 2);
    unsigned short* w1l    = (unsigned short*)take((size_t)4 * 256 * 128 * 2);
    _Float16*       whh16  = (_Float16*)take((size_t)4 * 512 * 128 * 2);     // 512 KB
    _Float16*       wih16  = (_Float16*)take((size_t)4 * 512 * 128 * 2);
    _Float16*       seqA   = (_Float16*)take((size_t)R2c * H1c * 2);         // 4.2 MB
    _Float16*       seqH   = (_Float16*)take((size_t)3 * R2c * H2c * 2);     // 25 MB
    float*          stats  = (float*)take(1024);
    float*          c2     = (float*)take((size_t)4 * 32 * 128 * 4);
    unsigned int*   flags  = (unsigned int*)take(256);

    auto prep = [&](const float* src, unsigned short* dh, unsigned short* dl,
                    int R, int K, int OS, int KO) {
        int n = R * K;
        k_prep<<<(n + 255) / 256, 256, 0, stream>>>(src, dh, dl, R, K, OS, KO);
    };
    auto prep16 = [&](const float* src, _Float16* dst, int n) {
        k_prep16<<<(n + 255) / 256, 256, 0, stream>>>(src, dst, n);
    };

    // LSTM1 combined [Wih | Whh] split-bf16, row stride 128
    prep(l1Wih0, w1h, w1l, 256, 32, 128, 0);
    prep(l1Whh0, w1h, w1l, 256, 64, 128, 32);
    for (int l = 1; l < 4; ++l) {
        prep(l1Wih + (l - 1) * 256 * 64, w1h + l * 256 * 128, w1l + l * 256 * 128, 256, 64, 128, 0);
        prep(l1Whh + (l - 1) * 256 * 64, w1h + l * 256 * 128, w1l + l * 256 * 128, 256, 64, 128, 64);
    }
    // LSTM2 fp16 weights
    prep16(l2Whh0, whh16, 512 * 128);
    for (int l = 1; l < 4; ++l)
        prep16(l2Whh + (l - 1) * 512 * 128, whh16 + (size_t)l * 512 * 128, 512 * 128);
    prep16(l2Wih0, wih16, 512 * 64);                       // layer0: stride 64
    for (int l = 1; l < 4; ++l)
        prep16(l2Wih + (l - 1) * 512 * 128, wih16 + (size_t)l * 512 * 128, 512 * 128);

    k_embed<<<(NTc * EMBc + 255) / 256, 256, 0, stream>>>(atoms, embw, seq1h, seq1l);

    for (int l = 0; l < 4; ++l) {
        const float* bp = (l == 0) ? l1b0 : l1b + (l - 1) * 256;
        if (l == 0)
            k_scan1<32><<<Ntot / 32, 256, 0, stream>>>(seq1h, seq1l, w1h, w1l, bp, dacc, 0, 1);
        else
            k_scan1<64><<<Ntot / 32, 256, 0, stream>>>(seq1h, seq1l,
                                                       w1h + l * 256 * 128, w1l + l * 256 * 128,
                                                       bp, dacc, 1, (l != 3) ? 1 : 0);
    }

    k_bn2_stats<<<32, 256, 0, stream>>>(lens, dacc, stats);
    k_bn2_apply<<<(R2c * H1c + 255) / 256, 256, 0, stream>>>(dacc, stats, lens, bn2g, bn2b, seqA);

    hipMemsetAsync(flags, 0, 16, stream);
    k_scan2_pipe<<<4, 512, 0, stream>>>(seqA, seqH, whh16, wih16, l2b0, l2b, c2, flags);

    k_head<<<1, 256, 0, stream>>>(c2, bn3g, bn3b, w1, b1, w2, b2, w22, b22,
                                  w3, b3, w4, b4, w5, b5, out);

    (void)in_sizes; (void)n_in; (void)out_size; (void)ws_size;
}